// Round 7
// baseline (220.962 us; speedup 1.0000x reference)
//
#include <hip/hip_runtime.h>

#define M_Q 50000
#define N_S 50000
#define H_N 32
#define K_P 15
#define C_IN 128
#define C_OUT 128
#define QB 64      // queries per block
#define NT 256     // threads per block (4 waves)
#define EMAX 24    // per-query entry capacity (mean ~2, P(>24) ~ 1e-18)

typedef __attribute__((ext_vector_type(8))) short s8v;      // 8 bf16 = MFMA A/B frag
typedef __attribute__((ext_vector_type(4))) float f4v;      // MFMA C/D frag
typedef __attribute__((ext_vector_type(4))) float fl4;
typedef __attribute__((ext_vector_type(4))) unsigned u4v;

union AF { u4v u; s8v s; };

static __device__ __forceinline__ unsigned f2bf_bits(float x) {
    union { float f; unsigned u; } v; v.f = x;
    return (v.u + 0x7fffu + ((v.u >> 16) & 1u)) >> 16;
}
static __device__ __forceinline__ unsigned pack_bf16(float a, float b) {
    return f2bf_bits(a) | (f2bf_bits(b) << 16);
}

// ---- pre-pass: W[k][c][d] fp32 -> fragment-major bf16 ----
// slot i: lane=i&63, kk=(i>>6)&3, col=(i>>8)&7, k=i>>11; elems j=0..7
// element: d = col*16 + (lane&15), c = kk*32 + (lane>>4)*8 + j
__global__ __launch_bounds__(256) void wcvt_frag(const float* __restrict__ W,
                                                 unsigned short* __restrict__ Wtf) {
    int i = blockIdx.x * 256 + threadIdx.x;
    if (i >= K_P * 8 * 4 * 64) return;
    const int lane = i & 63;
    const int kk = (i >> 6) & 3;
    const int col = (i >> 8) & 7;
    const int k = i >> 11;
    const int d = col * 16 + (lane & 15);
    const int c0 = kk * 32 + (lane >> 4) * 8;
    unsigned short* dst = Wtf + (size_t)i * 8;
    #pragma unroll
    for (int j = 0; j < 8; ++j)
        dst[j] = (unsigned short)f2bf_bits(W[((size_t)k * 128 + c0 + j) * 128 + d]);
}

// ---- main: sorted entry lists + barrier-free k-loop, B direct from global ----
// Each of 4 waves: all 4 m-tiles (64 q) x 2 n-columns (32 d).
template <typename IT>
__global__ __launch_bounds__(NT, 3) void kpconv_v7(
    const float* __restrict__ q_pts,
    const float* __restrict__ s_pts,
    const float* __restrict__ s_feats,
    const IT* __restrict__ inds,
    const float* __restrict__ kernel_points,
    const unsigned short* __restrict__ Wtf,  // frag-major bf16
    float* __restrict__ out)
{
    __shared__ float s_ew[QB][EMAX];         // entry weights
    __shared__ unsigned s_em[QB][EMAX];      // (k<<16)|idx, sorted by k
    __shared__ int s_cnt[QB];
    __shared__ float s_kp[K_P * 3];
    __shared__ float s_q[QB * 3];

    const int t = threadIdx.x;
    const int lane = t & 63;
    const int w = t >> 6;                    // wave 0..3
    const int quad = lane >> 4, l15 = lane & 15;
    const int qbase = blockIdx.x * QB;

    if (t < K_P * 3) s_kp[t] = kernel_points[t];
    if (t < QB) s_cnt[t] = 0;
    if (t < QB * 3) {
        int g = qbase * 3 + t;
        s_q[t] = (g < M_Q * 3) ? q_pts[g] : 0.0f;
    }
    __syncthreads();

    // ---- phase 1: geometry -> unsorted per-q entry lists (2048 tasks) ----
    #pragma unroll
    for (int it = 0; it < 8; ++it) {
        const int task = it * NT + t;
        const int q = task >> 5, h = task & 31;
        const int qg = qbase + q;
        if (qg < M_Q) {
            long long idx = (long long)inds[(size_t)qg * H_N + h];
            if ((unsigned long long)idx < (unsigned long long)N_S) {
                const int i32 = (int)idx;
                const float rx = s_pts[i32 * 3 + 0] - s_q[q * 3 + 0];
                const float ry = s_pts[i32 * 3 + 1] - s_q[q * 3 + 1];
                const float rz = s_pts[i32 * 3 + 2] - s_q[q * 3 + 2];
                #pragma unroll
                for (int k = 0; k < K_P; ++k) {
                    const float dx = rx - s_kp[k * 3 + 0];
                    const float dy = ry - s_kp[k * 3 + 1];
                    const float dz = rz - s_kp[k * 3 + 2];
                    const float d2 = dx * dx + dy * dy + dz * dz;
                    if (d2 < 1.0f) {             // w>0 <=> d2<1 (exact zero-skip)
                        const float wgt = 1.0f - sqrtf(d2);
                        const int pos = atomicAdd(&s_cnt[q], 1);
                        if (pos < EMAX) {
                            s_ew[q][pos] = wgt;
                            s_em[q][pos] = ((unsigned)k << 16) | (unsigned)i32;
                        }
                    }
                }
            }
        }
    }
    __syncthreads();

    // ---- sort each query's list by k (tiny insertion sort) ----
    if (t < QB) {
        const int n = min(s_cnt[t], EMAX);
        s_cnt[t] = n;
        for (int i = 1; i < n; ++i) {
            const unsigned mi = s_em[t][i];
            const float wi = s_ew[t][i];
            int j = i - 1;
            while (j >= 0 && s_em[t][j] > mi) {
                s_em[t][j + 1] = s_em[t][j];
                s_ew[t][j + 1] = s_ew[t][j];
                --j;
            }
            s_em[t][j + 1] = mi;
            s_ew[t][j + 1] = wi;
        }
    }
    __syncthreads();   // LAST barrier — k-loop below is fully barrier-free

    // ---- per-lane walker state for the 4 owned rows (q = mt*16 + l15) ----
    int ptr[4], ecnt[4];
    unsigned meta[4];
    #pragma unroll
    for (int mt = 0; mt < 4; ++mt) {
        const int q = mt * 16 + l15;
        ecnt[mt] = s_cnt[q];
        ptr[mt] = 0;
        meta[mt] = (ecnt[mt] > 0) ? s_em[q][0] : 0xffffffffu;
    }

    const f4v zf = {0.0f, 0.0f, 0.0f, 0.0f};
    f4v acc[4][2];
    #pragma unroll
    for (int mt = 0; mt < 4; ++mt) { acc[mt][0] = zf; acc[mt][1] = zf; }

    float va[4][8];                  // fp32 A scratch, zero unless mid-build
    #pragma unroll
    for (int kk = 0; kk < 4; ++kk)
        #pragma unroll
        for (int j = 0; j < 8; ++j) va[kk][j] = 0.0f;

    for (int k = 0; k < K_P; ++k) {
        // B-frags for this k: 2 cols x 4 kk, coalesced 16B/lane, L2-resident
        u4v b[2][4];
        #pragma unroll
        for (int nc = 0; nc < 2; ++nc) {
            const int c8 = w * 2 + nc;
            const u4v* bsrc = ((const u4v*)Wtf) + ((((size_t)k * 8 + c8) * 4) * 64 + lane);
            #pragma unroll
            for (int kk = 0; kk < 4; ++kk) b[nc][kk] = bsrc[kk * 64];
        }

        #pragma unroll
        for (int mt = 0; mt < 4; ++mt) {
            const int q = mt * 16 + l15;
            bool built = false;
            while (true) {
                const bool m = ((int)(meta[mt] >> 16) == k);
                if (!__any(m)) break;
                if (m) {
                    const float wgt = s_ew[q][ptr[mt]];
                    const float* fr = s_feats + (size_t)(meta[mt] & 0xffffu) * C_IN + quad * 8;
                    #pragma unroll
                    for (int kk = 0; kk < 4; ++kk) {
                        const fl4 f0 = *(const fl4*)(fr + kk * 32);
                        const fl4 f1 = *(const fl4*)(fr + kk * 32 + 4);
                        va[kk][0] = fmaf(wgt, f0.x, va[kk][0]);
                        va[kk][1] = fmaf(wgt, f0.y, va[kk][1]);
                        va[kk][2] = fmaf(wgt, f0.z, va[kk][2]);
                        va[kk][3] = fmaf(wgt, f0.w, va[kk][3]);
                        va[kk][4] = fmaf(wgt, f1.x, va[kk][4]);
                        va[kk][5] = fmaf(wgt, f1.y, va[kk][5]);
                        va[kk][6] = fmaf(wgt, f1.z, va[kk][6]);
                        va[kk][7] = fmaf(wgt, f1.w, va[kk][7]);
                    }
                    built = true;
                    ++ptr[mt];
                    meta[mt] = (ptr[mt] < ecnt[mt]) ? s_em[q][ptr[mt]] : 0xffffffffu;
                }
            }
            const unsigned long long anyb = __ballot(built);
            if (anyb) {
                AF af[4];
                if (built) {
                    #pragma unroll
                    for (int kk = 0; kk < 4; ++kk) {
                        af[kk].u[0] = pack_bf16(va[kk][0], va[kk][1]);
                        af[kk].u[1] = pack_bf16(va[kk][2], va[kk][3]);
                        af[kk].u[2] = pack_bf16(va[kk][4], va[kk][5]);
                        af[kk].u[3] = pack_bf16(va[kk][6], va[kk][7]);
                        #pragma unroll
                        for (int j = 0; j < 8; ++j) va[kk][j] = 0.0f;
                    }
                } else {
                    #pragma unroll
                    for (int kk = 0; kk < 4; ++kk) af[kk].u = (u4v){0u, 0u, 0u, 0u};
                }
                #pragma unroll
                for (int nc = 0; nc < 2; ++nc)
                    #pragma unroll
                    for (int kk = 0; kk < 4; ++kk)
                        acc[mt][nc] = __builtin_amdgcn_mfma_f32_16x16x32_bf16(
                            af[kk].s, *(const s8v*)&b[nc][kk], acc[mt][nc], 0, 0, 0);
            }
        }
    }

    // ---- epilogue: C/D layout col=lane&15, row=quad*4+reg ----
    #pragma unroll
    for (int mt = 0; mt < 4; ++mt) {
        #pragma unroll
        for (int nc = 0; nc < 2; ++nc) {
            #pragma unroll
            for (int r = 0; r < 4; ++r) {
                const int qg = qbase + mt * 16 + quad * 4 + r;
                if (qg < M_Q)
                    out[(size_t)qg * C_OUT + (w * 2 + nc) * 16 + l15] = acc[mt][nc][r];
            }
        }
    }
}

extern "C" void kernel_launch(void* const* d_in, const int* in_sizes, int n_in,
                              void* d_out, int out_size, void* d_ws, size_t ws_size,
                              hipStream_t stream) {
    const float* q_pts         = (const float*)d_in[0];
    const float* s_pts         = (const float*)d_in[1];
    const float* s_feats       = (const float*)d_in[2];
    const float* kernel_points = (const float*)d_in[4];
    const float* weights       = (const float*)d_in[5];
    float* out = (float*)d_out;
    const bool i64 = (in_sizes[3] == 2 * M_Q * H_N);

    unsigned short* Wtf = (unsigned short*)d_ws;
    const int slots = K_P * 8 * 4 * 64;
    wcvt_frag<<<(slots + 255) / 256, 256, 0, stream>>>(weights, Wtf);

    dim3 grid((M_Q + QB - 1) / QB), block(NT);
    if (i64)
        kpconv_v7<long long><<<grid, block, 0, stream>>>(
            q_pts, s_pts, s_feats, (const long long*)d_in[3], kernel_points, Wtf, out);
    else
        kpconv_v7<int><<<grid, block, 0, stream>>>(
            q_pts, s_pts, s_feats, (const int*)d_in[3], kernel_points, Wtf, out);
}

// Round 8
// 159.517 us; speedup vs baseline: 1.3852x; 1.3852x over previous
//
#include <hip/hip_runtime.h>

#define M_Q 50000
#define N_S 50000
#define H_N 32
#define K_P 15
#define C_IN 128
#define C_OUT 128

// K1 geometry
#define G_QB 64
#define G_NT 256
#define NB_GEO ((M_Q + G_QB - 1) / G_QB)      // 782
#define LCAP 64                                // per-k LDS staging (Poisson mean 8.6)

// W conversion folded into K1 tail blocks
#define WTF_SLOTS (K_P * 8 * 4 * 64)           // 30720 16B slots
#define NB_WCVT (WTF_SLOTS / 256)              // 120

// K2
#define ENT 96                                 // entries per K2 block
#define SUBT (ENT / 16)                        // 6 m-subtiles
#define CAPK 12288                             // bucket capacity per k (mean 6700)
#define K2_TILES (CAPK / ENT)                  // 128

// ws layout
#define WS_CNT_OFF 0
#define WS_WTF_OFF 256
#define WS_WTF_BYTES (WTF_SLOTS * 16)          // 491520
#define WS_BKT_OFF (WS_WTF_OFF + WS_WTF_BYTES)
#define WS_BKT_BYTES (K_P * CAPK * 8)          // 1474560
#define WS_NEED (WS_BKT_OFF + WS_BKT_BYTES)

typedef __attribute__((ext_vector_type(8))) short s8v;
typedef __attribute__((ext_vector_type(4))) float f4v;
typedef __attribute__((ext_vector_type(4))) float fl4;
typedef __attribute__((ext_vector_type(4))) unsigned u4v;

static __device__ __forceinline__ unsigned f2bf_bits(float x) {
    union { float f; unsigned u; } v; v.f = x;
    return (v.u + 0x7fffu + ((v.u >> 16) & 1u)) >> 16;
}
static __device__ __forceinline__ unsigned pack_bf16(float a, float b) {
    return f2bf_bits(a) | (f2bf_bits(b) << 16);
}

// ============ K1: geometry -> per-k entry buckets; tail blocks convert W ============
template <typename IT>
__global__ __launch_bounds__(G_NT) void k1_geom(
    const float* __restrict__ q_pts,
    const float* __restrict__ s_pts,
    const IT* __restrict__ inds,
    const float* __restrict__ kp,
    const float* __restrict__ W,
    unsigned* __restrict__ ws_u)
{
    const int b = blockIdx.x;
    const int t = threadIdx.x;

    if (b >= NB_GEO) {
        // ---- W[k][c][d] fp32 -> Wtf frag-major bf16 ----
        const int i = (b - NB_GEO) * 256 + t;
        if (i < WTF_SLOTS) {
            const int lane = i & 63;
            const int kk = (i >> 6) & 3;
            const int col = (i >> 8) & 7;
            const int k = i >> 11;
            const int d = col * 16 + (lane & 15);
            const int c0 = kk * 32 + (lane >> 4) * 8;
            unsigned short* dst =
                (unsigned short*)((char*)ws_u + WS_WTF_OFF) + (size_t)i * 8;
            #pragma unroll
            for (int j = 0; j < 8; ++j)
                dst[j] = (unsigned short)f2bf_bits(W[((size_t)k * 128 + c0 + j) * 128 + d]);
        }
        return;
    }

    __shared__ float s_kp[K_P * 3];
    __shared__ float s_q[G_QB * 3];
    __shared__ int s_lcnt[K_P];
    __shared__ uint2 s_le[K_P][LCAP];
    __shared__ int s_gb[K_P], s_gc[K_P];

    const int qbase = b * G_QB;
    if (t < K_P * 3) s_kp[t] = kp[t];
    if (t < K_P) s_lcnt[t] = 0;
    if (t < G_QB * 3) {
        int g = qbase * 3 + t;
        s_q[t] = (g < M_Q * 3) ? q_pts[g] : 0.0f;
    }
    __syncthreads();

    #pragma unroll
    for (int it = 0; it < 8; ++it) {
        const int task = it * G_NT + t;          // 2048 = 64q x 32h
        const int q = task >> 5, h = task & 31;
        const int qg = qbase + q;
        if (qg < M_Q) {
            long long idx = (long long)inds[(size_t)qg * H_N + h];
            if ((unsigned long long)idx < (unsigned long long)N_S) {
                const int i32 = (int)idx;
                const float rx = s_pts[i32 * 3 + 0] - s_q[q * 3 + 0];
                const float ry = s_pts[i32 * 3 + 1] - s_q[q * 3 + 1];
                const float rz = s_pts[i32 * 3 + 2] - s_q[q * 3 + 2];
                #pragma unroll
                for (int k = 0; k < K_P; ++k) {
                    const float dx = rx - s_kp[k * 3 + 0];
                    const float dy = ry - s_kp[k * 3 + 1];
                    const float dz = rz - s_kp[k * 3 + 2];
                    const float d2 = dx * dx + dy * dy + dz * dz;
                    if (d2 < 1.0f) {             // w>0 <=> d2<1 (exact zero-skip)
                        const float wgt = 1.0f - sqrtf(d2);
                        const int pos = atomicAdd(&s_lcnt[k], 1);
                        if (pos < LCAP)
                            s_le[k][pos] = make_uint2(((unsigned)qg << 16) | (unsigned)i32,
                                                      __float_as_uint(wgt));
                    }
                }
            }
        }
    }
    __syncthreads();

    if (t < K_P) {
        const int cl = min(s_lcnt[t], LCAP);
        const int base = (int)atomicAdd(&ws_u[t], (unsigned)cl);
        s_gb[t] = base;
        const int avail = CAPK - base;
        s_gc[t] = max(0, min(cl, avail));
    }
    __syncthreads();

    uint2* bkt = (uint2*)((char*)ws_u + WS_BKT_OFF);
    #pragma unroll
    for (int k = 0; k < K_P; ++k) {
        if (t < s_gc[k])
            bkt[(size_t)k * CAPK + s_gb[k] + t] = s_le[k][t];
    }
}

// ============ K2: per-(k, entry-tile) GEMM with scatter-add ============
__global__ __launch_bounds__(256, 2) void k2_gemm(
    const float* __restrict__ s_feats,
    const unsigned* __restrict__ ws_u,
    float* __restrict__ out)
{
    const int k = blockIdx.x;
    const int base = blockIdx.y * ENT;
    const int cnt = min((int)ws_u[k], CAPK);
    int n_e = cnt - base;
    if (n_e <= 0) return;
    if (n_e > ENT) n_e = ENT;

    __shared__ unsigned short s_A[SUBT * 4 * 64 * 8];   // 24 KB frag-major A
    __shared__ unsigned short s_W[8 * 4 * 64 * 8];      // 32 KB frag-major W_k
    __shared__ unsigned s_mi[ENT];

    const int t = threadIdx.x;
    const int lane = t & 63;
    const int w = t >> 6;
    const int quad = lane >> 4, l15 = lane & 15;

    // ---- stage W_k (coalesced 32 KB copy, frag order preserved) ----
    {
        const u4v* wsrc = (const u4v*)((const char*)ws_u + WS_WTF_OFF) + (size_t)k * 2048;
        u4v* wdst = (u4v*)s_W;
        #pragma unroll
        for (int j = 0; j < 8; ++j) wdst[t + j * 256] = wsrc[t + j * 256];
    }

    // ---- stage A: each row gathered once, scaled, packed frag-major ----
    const int e = t >> 1, half = t & 1;
    if (e < ENT) {
        const int sub = e >> 4, l15e = e & 15;
        if (e < n_e) {
            const uint2* bkt = (const uint2*)((const char*)ws_u + WS_BKT_OFF)
                               + (size_t)k * CAPK + base;
            const uint2 be = bkt[e];
            const unsigned mi = be.x;
            const float wgt = __uint_as_float(be.y);
            if (half == 0) s_mi[e] = mi;
            const float* fr = s_feats + (size_t)(mi & 0xffffu) * C_IN + half * 64;
            #pragma unroll
            for (int j = 0; j < 4; ++j) {
                const fl4 fa = *(const fl4*)(fr + j * 16);
                const fl4 fb = *(const fl4*)(fr + j * 16 + 4);
                const fl4 fc = *(const fl4*)(fr + j * 16 + 8);
                const fl4 fd = *(const fl4*)(fr + j * 16 + 12);
                u4v g0, g1;
                g0[0] = pack_bf16(wgt * fa.x, wgt * fa.y);
                g0[1] = pack_bf16(wgt * fa.z, wgt * fa.w);
                g0[2] = pack_bf16(wgt * fb.x, wgt * fb.y);
                g0[3] = pack_bf16(wgt * fb.z, wgt * fb.w);
                g1[0] = pack_bf16(wgt * fc.x, wgt * fc.y);
                g1[1] = pack_bf16(wgt * fc.z, wgt * fc.w);
                g1[2] = pack_bf16(wgt * fd.x, wgt * fd.y);
                g1[3] = pack_bf16(wgt * fd.z, wgt * fd.w);
                const int cs = half * 64 + j * 16;
                const int kk = cs >> 5;
                const int qd = (cs >> 3) & 3;    // 0 or 2
                *(u4v*)&s_A[(size_t)(((sub * 4 + kk) * 64) + qd * 16 + l15e) * 8] = g0;
                *(u4v*)&s_A[(size_t)(((sub * 4 + kk) * 64) + (qd + 1) * 16 + l15e) * 8] = g1;
            }
        } else {
            if (half == 0) s_mi[e] = 0xffffffffu;
            const u4v z = {0u, 0u, 0u, 0u};
            #pragma unroll
            for (int j = 0; j < 4; ++j) {
                const int cs = half * 64 + j * 16;
                const int kk = cs >> 5;
                const int qd = (cs >> 3) & 3;
                *(u4v*)&s_A[(size_t)(((sub * 4 + kk) * 64) + qd * 16 + l15e) * 8] = z;
                *(u4v*)&s_A[(size_t)(((sub * 4 + kk) * 64) + (qd + 1) * 16 + l15e) * 8] = z;
            }
        }
    }
    __syncthreads();   // the ONLY barrier

    // ---- MFMA: wave w owns d-cols [w*32, w*32+32) ----
    s8v bf[2][4];
    #pragma unroll
    for (int nc = 0; nc < 2; ++nc)
        #pragma unroll
        for (int kk = 0; kk < 4; ++kk)
            bf[nc][kk] = *(const s8v*)&s_W[(size_t)((((w * 2 + nc) * 4) + kk) * 64 + lane) * 8];

    const f4v zf = {0.0f, 0.0f, 0.0f, 0.0f};
    f4v acc[SUBT][2];
    #pragma unroll
    for (int s = 0; s < SUBT; ++s) { acc[s][0] = zf; acc[s][1] = zf; }

    #pragma unroll
    for (int s = 0; s < SUBT; ++s) {
        s8v af[4];
        #pragma unroll
        for (int kk = 0; kk < 4; ++kk)
            af[kk] = *(const s8v*)&s_A[(size_t)((s * 4 + kk) * 64 + lane) * 8];
        #pragma unroll
        for (int nc = 0; nc < 2; ++nc)
            #pragma unroll
            for (int kk = 0; kk < 4; ++kk)
                acc[s][nc] = __builtin_amdgcn_mfma_f32_16x16x32_bf16(
                    af[kk], bf[nc][kk], acc[s][nc], 0, 0, 0);
    }

    // ---- epilogue: scatter-add (C/D: col=l15, row=quad*4+r) ----
    #pragma unroll
    for (int s = 0; s < SUBT; ++s) {
        #pragma unroll
        for (int r = 0; r < 4; ++r) {
            const unsigned mi = s_mi[s * 16 + quad * 4 + r];
            const unsigned m = mi >> 16;
            if (m < M_Q) {
                float* op = out + (size_t)m * C_OUT + w * 32 + l15;
                atomicAdd(op,      acc[s][0][r]);
                atomicAdd(op + 16, acc[s][1][r]);
            }
        }
    }
}

// ============ fallback (V1, workspace-free) ============
template <typename IT>
__global__ __launch_bounds__(128, 8) void kpconv_v1(
    const float* __restrict__ q_pts, const float* __restrict__ s_pts,
    const float* __restrict__ s_feats, const IT* __restrict__ neighb_inds,
    const float* __restrict__ kernel_points, const float* __restrict__ weights,
    float* __restrict__ out)
{
    __shared__ float s_kp[K_P * 3];
    __shared__ float s_w[K_P][H_N];
    __shared__ int s_idx[H_N];
    __shared__ unsigned s_hmask, s_kmask;
    __shared__ float s_wf[K_P][C_IN];
    const int m = blockIdx.x, tid = threadIdx.x;
    if (tid < K_P * 3) s_kp[tid] = kernel_points[tid];
    if (tid == 0) { s_hmask = 0u; s_kmask = 0u; }
    __syncthreads();
    if (tid < H_N) {
        long long idx = (long long)neighb_inds[(size_t)m * H_N + tid];
        const float qx = q_pts[m * 3], qy = q_pts[m * 3 + 1], qz = q_pts[m * 3 + 2];
        float rx, ry, rz; int idx32;
        if ((unsigned long long)idx < (unsigned long long)N_S) {
            idx32 = (int)idx;
            rx = s_pts[idx32 * 3] - qx; ry = s_pts[idx32 * 3 + 1] - qy; rz = s_pts[idx32 * 3 + 2] - qz;
        } else { idx32 = 0; rx = ry = rz = 1.0e6f; }
        s_idx[tid] = idx32;
        unsigned kmask = 0u;
        #pragma unroll
        for (int k = 0; k < K_P; ++k) {
            const float dx = rx - s_kp[k * 3], dy = ry - s_kp[k * 3 + 1], dz = rz - s_kp[k * 3 + 2];
            const float w = fmaxf(1.0f - sqrtf(dx * dx + dy * dy + dz * dz), 0.0f);
            s_w[k][tid] = w;
            if (w > 0.0f) kmask |= (1u << k);
        }
        if (kmask) { atomicOr(&s_hmask, 1u << tid); atomicOr(&s_kmask, kmask); }
    }
    __syncthreads();
    const unsigned hmask = s_hmask, kmask = s_kmask;
    float wf[K_P];
    #pragma unroll
    for (int k = 0; k < K_P; ++k) wf[k] = 0.0f;
    unsigned hmv = hmask;
    while (hmv) {
        const int h = __builtin_ctz(hmv); hmv &= hmv - 1;
        const float f = s_feats[(size_t)s_idx[h] * C_IN + tid];
        #pragma unroll
        for (int k = 0; k < K_P; ++k) wf[k] = fmaf(s_w[k][h], f, wf[k]);
    }
    #pragma unroll
    for (int k = 0; k < K_P; ++k) s_wf[k][tid] = wf[k];
    __syncthreads();
    float a = 0.0f;
    unsigned km = kmask;
    while (km) {
        const int k = __builtin_ctz(km); km &= km - 1;
        const float* Wk = weights + (size_t)k * C_IN * C_OUT + tid;
        #pragma unroll 8
        for (int c = 0; c < C_IN; ++c) a = fmaf(s_wf[k][c], Wk[(size_t)c * C_OUT], a);
    }
    out[(size_t)m * C_OUT + tid] = a;
}

extern "C" void kernel_launch(void* const* d_in, const int* in_sizes, int n_in,
                              void* d_out, int out_size, void* d_ws, size_t ws_size,
                              hipStream_t stream) {
    const float* q_pts         = (const float*)d_in[0];
    const float* s_pts         = (const float*)d_in[1];
    const float* s_feats       = (const float*)d_in[2];
    const float* kernel_points = (const float*)d_in[4];
    const float* weights       = (const float*)d_in[5];
    float* out = (float*)d_out;
    const bool i64 = (in_sizes[3] == 2 * M_Q * H_N);

    if (ws_size < (size_t)WS_NEED) {
        dim3 grid(M_Q), block(128);
        if (i64)
            kpconv_v1<long long><<<grid, block, 0, stream>>>(
                q_pts, s_pts, s_feats, (const long long*)d_in[3], kernel_points, weights, out);
        else
            kpconv_v1<int><<<grid, block, 0, stream>>>(
                q_pts, s_pts, s_feats, (const int*)d_in[3], kernel_points, weights, out);
        return;
    }

    unsigned* ws_u = (unsigned*)d_ws;
    hipMemsetAsync(d_ws, 0, 64, stream);                                 // counters
    hipMemsetAsync(d_out, 0, (size_t)out_size * sizeof(float), stream);  // accumulators

    dim3 g1(NB_GEO + NB_WCVT), b1(G_NT);
    if (i64)
        k1_geom<long long><<<g1, b1, 0, stream>>>(
            q_pts, s_pts, (const long long*)d_in[3], kernel_points, weights, ws_u);
    else
        k1_geom<int><<<g1, b1, 0, stream>>>(
            q_pts, s_pts, (const int*)d_in[3], kernel_points, weights, ws_u);

    dim3 g2(K_P, K2_TILES), b2(256);
    k2_gemm<<<g2, b2, 0, stream>>>(s_feats, ws_u, out);
}